// Round 15
// baseline (594.197 us; speedup 1.0000x reference)
//
#include <hip/hip_runtime.h>
#include <hip/hip_bf16.h>

typedef float f32x4 __attribute__((ext_vector_type(4)));
typedef __bf16 bf16x8 __attribute__((ext_vector_type(8)));

#define N 8192
#define CH 256
#define NJC 2            // j-chunks (R9 pipeline)
#define JCW (N / NJC)    // 4096 j per chunk
#define JT 128           // j per tile
#define NT (JCW / JT)    // 32 tiles per chunk
#define BM 64            // rows per block

// ---- workspace layout (bytes) ----
static constexpr size_t OFF_P1 = 0;
static constexpr size_t OFF_P2 = 32768;
static constexpr size_t OFF_T1 = 65536;
static constexpr size_t OFF_T2 = 66560;
static constexpr size_t OFF_F1 = 67584;
static constexpr size_t OFF_F2 = OFF_F1 + (size_t)N * 4;
static constexpr size_t OFF_XT = 262144;                       // packed B, 4 MB
static constexpr size_t OFF_SP = OFF_XT + (size_t)CH * N * 2;  // 2x8192 f32
static constexpr size_t OFF_PV = OFF_SP + (size_t)NJC * N * 4; // 1x8 MB
// ablation scratch (never validated)
static constexpr size_t OFF_AB_PART = (size_t)128 * 1024 * 1024;  // 64 MB
static constexpr size_t OFF_AB_S    = (size_t)200 * 1024 * 1024;  // 256 KB

// K1a: partial t-vectors over h-slices of 8.
__global__ __launch_bounds__(256) void k1a(
    const float* __restrict__ W, const float* __restrict__ w1,
    const float* __restrict__ w2, float* __restrict__ p1, float* __restrict__ p2)
{
    int b = blockIdx.x, c = threadIdx.x;
    float a1 = 0.f, a2 = 0.f;
#pragma unroll
    for (int hh = 0; hh < 8; ++hh) {
        int h = b * 8 + hh;
        float wv = W[h * CH + c];
        a1 = __builtin_fmaf(w1[h], wv, a1);
        a2 = __builtin_fmaf(w2[h], wv, a2);
    }
    p1[b * CH + c] = a1;
    p2[b * CH + c] = a2;
}

// K1b: fold 32 partials -> t1,t2.
__global__ __launch_bounds__(256) void k1b(
    const float* __restrict__ p1, const float* __restrict__ p2,
    float* __restrict__ t1, float* __restrict__ t2)
{
    int c = threadIdx.x;
    float a1 = 0.f, a2 = 0.f;
#pragma unroll 8
    for (int b = 0; b < 32; ++b) { a1 += p1[b * CH + c]; a2 += p2[b * CH + c]; }
    t1[c] = a1;
    t2[c] = a2;
}

// KTF: fused pack + f1/f2. inlayer [N][CH] f32 -> xtp fragment-packed bf16 and
// per-row dots f1,f2.
__global__ __launch_bounds__(256) void ktf(
    const float* __restrict__ x, const float* __restrict__ t1,
    const float* __restrict__ t2, const float* __restrict__ b1,
    const float* __restrict__ b2, unsigned short* __restrict__ xtp,
    float* __restrict__ f1, float* __restrict__ f2)
{
    __shared__ unsigned short tile[32][264];     // +8 pad
    int js32 = blockIdx.x;
    int jb = js32 * 32;
    int t = threadIdx.x;
    int lane = t & 63;
    int wv = t >> 6;
    const float4* t1v = (const float4*)t1;
    const float4* t2v = (const float4*)t2;
    float4 ta = t1v[lane], tb = t2v[lane];
    float bb1 = b1[0], bb2 = b2[0];
#pragma unroll
    for (int it = 0; it < 8; ++it) {
        int jr = it * 4 + wv;
        float4 v = *(const float4*)(x + (size_t)(jb + jr) * CH + lane * 4);
        __hip_bfloat16 h0 = __float2bfloat16(v.x);
        __hip_bfloat16 h1 = __float2bfloat16(v.y);
        __hip_bfloat16 h2 = __float2bfloat16(v.z);
        __hip_bfloat16 h3 = __float2bfloat16(v.w);
        tile[jr][lane * 4 + 0] = *(unsigned short*)&h0;
        tile[jr][lane * 4 + 1] = *(unsigned short*)&h1;
        tile[jr][lane * 4 + 2] = *(unsigned short*)&h2;
        tile[jr][lane * 4 + 3] = *(unsigned short*)&h3;
        float d1 = v.x * ta.x + v.y * ta.y + v.z * ta.z + v.w * ta.w;
        float d2 = v.x * tb.x + v.y * tb.y + v.z * tb.z + v.w * tb.w;
#pragma unroll
        for (int off = 32; off; off >>= 1) {
            d1 += __shfl_down(d1, off);
            d2 += __shfl_down(d2, off);
        }
        if (lane == 0) { f1[jb + jr] = d1 + bb1; f2[jb + jr] = d2 + bb2; }
    }
    __syncthreads();
    int r = lane & 15, q = lane >> 4;
#pragma unroll
    for (int pass = 0; pass < 4; ++pass) {
        int ct = pass * 4 + wv;
        unsigned short vs[8];
#pragma unroll
        for (int e = 0; e < 8; ++e) vs[e] = tile[q * 8 + e][ct * 16 + r];
        size_t u = ((size_t)ct * 256 + js32) * 64 + lane;
        *(ulonglong2*)(xtp + u * 8) = *(ulonglong2*)vs;
    }
}

// Raw barrier: LDS visibility only; global loads stay in flight per-wave.
#define BAR() { asm volatile("s_waitcnt lgkmcnt(0)" ::: "memory"); \
                __builtin_amdgcn_s_barrier(); }

// K34 v9 (R9 verbatim): producer/consumer wave specialization.
__global__ __launch_bounds__(1024, 4) void k34_fused(
    const int* __restrict__ adj, const float* __restrict__ f1,
    const float* __restrict__ f2, const unsigned short* __restrict__ xtp,
    float* __restrict__ pv0, float* __restrict__ pvx, float* __restrict__ s_part)
{
    __shared__ __align__(16) unsigned short P[2][BM * JT];   // 2 x 16 KB
    __shared__ __align__(16) float f2s[JCW];                 // 16 KB

    const int tid = threadIdx.x;
    const int lane = tid & 63;
    const int w = tid >> 6;              // wave 0..15
    const int r = lane & 15, q = lane >> 4;
    const int bid = blockIdx.x;
    const int jc = bid & 1;              // j-chunk
    const int rb = (bid >> 1) * BM;
    const int jbase = jc * JCW;
    const bool cons = (w < 8);

    const int ptid = tid - 512;
    const int prow = (ptid >> 3) & 63;
    const int pjo = (ptid & 7) * 16;
    const int* aptr = adj + (size_t)(rb + prow) * N + jbase + pjo;
    const int s0i = (ptid & 7) * 2;
    const int wu0 = prow * 16 + (s0i ^ (prow & 7));
    const int wu1 = prow * 16 + ((s0i + 1) ^ (prow & 7));
    float f1r = 0.f;
    if (!cons) f1r = f1[rb + prow];

    const unsigned short* xb0 = xtp + (((size_t)(w * 2) * 256 + jc * (JCW / 32)) * 64 + lane) * 8;
    const unsigned short* xb1 = xtp + (((size_t)(w * 2 + 1) * 256 + jc * (JCW / 32)) * 64 + lane) * 8;

    f32x4 acc[4][2];
#pragma unroll
    for (int mt = 0; mt < 4; ++mt)
#pragma unroll
        for (int nt = 0; nt < 2; ++nt) acc[mt][nt] = (f32x4){0.f, 0.f, 0.f, 0.f};
    float s_acc = 0.f;

    int4 RA0, RA1, RA2, RA3, RB0, RB1, RB2, RB3;

#define LOAD_A(R0, R1, R2, R3, t)                                   \
    { const int4* p_ = (const int4*)(aptr + (size_t)(t) * JT);      \
      R0 = p_[0]; R1 = p_[1]; R2 = p_[2]; R3 = p_[3]; }
#define EXPW(R0, R1, R2, R3, buf, tt)                               \
    { float4 g0 = *(const float4*)(&f2s[(tt) * JT + pjo]);          \
      float4 g1 = *(const float4*)(&f2s[(tt) * JT + pjo + 4]);      \
      float4 g2 = *(const float4*)(&f2s[(tt) * JT + pjo + 8]);      \
      float4 g3 = *(const float4*)(&f2s[(tt) * JT + pjo + 12]);     \
      int av[16] = {R0.x, R0.y, R0.z, R0.w, R1.x, R1.y, R1.z, R1.w, \
                    R2.x, R2.y, R2.z, R2.w, R3.x, R3.y, R3.z, R3.w};\
      float gv[16] = {g0.x, g0.y, g0.z, g0.w, g1.x, g1.y, g1.z, g1.w,\
                      g2.x, g2.y, g2.z, g2.w, g3.x, g3.y, g3.z, g3.w};\
      bf16x8 pk0, pk1;                                              \
      _Pragma("unroll")                                             \
      for (int e = 0; e < 16; ++e) {                                \
          float t_ = f1r + gv[e];                                   \
          t_ = fmaxf(t_, 0.01f * t_);                               \
          float p_ = (av[e] > 0) ? __expf(t_) : 0.f;                \
          s_acc += p_;                                              \
          if (e < 8) pk0[e] = (__bf16)p_; else pk1[e - 8] = (__bf16)p_; \
      }                                                             \
      *reinterpret_cast<bf16x8*>(&P[buf][(size_t)wu0 * 8]) = pk0;   \
      *reinterpret_cast<bf16x8*>(&P[buf][(size_t)wu1 * 8]) = pk1; }
#define MFMA_TILE(tt, buf)                                          \
    { _Pragma("unroll")                                             \
      for (int kk = 0; kk < 4; ++kk) {                              \
          bf16x8 B0 = *(const bf16x8*)(xb0 + ((size_t)((tt) * 4 + kk) * 64) * 8); \
          bf16x8 B1 = *(const bf16x8*)(xb1 + ((size_t)((tt) * 4 + kk) * 64) * 8); \
          _Pragma("unroll")                                         \
          for (int mt = 0; mt < 4; ++mt) {                          \
              int u_ = (mt * 16 + r) * 16 + ((kk * 4 + q) ^ (r & 7)); \
              bf16x8 A = *(const bf16x8*)(&P[buf][(size_t)u_ * 8]); \
              acc[mt][0] = __builtin_amdgcn_mfma_f32_16x16x32_bf16(A, B0, acc[mt][0], 0, 0, 0); \
              acc[mt][1] = __builtin_amdgcn_mfma_f32_16x16x32_bf16(A, B1, acc[mt][1], 0, 0, 0); \
          }                                                         \
      } }

    *(float4*)(&f2s[tid * 4]) = *(const float4*)(f2 + jbase + tid * 4);

    if (!cons) {
        LOAD_A(RA0, RA1, RA2, RA3, 0);
        LOAD_A(RB0, RB1, RB2, RB3, 1);
    }
    __syncthreads();
    if (!cons) EXPW(RA0, RA1, RA2, RA3, 0, 0);
    BAR();

    for (int t = 0; t < NT; t += 2) {
        if (cons) {
            MFMA_TILE(t, 0);
        } else {
            if (t + 2 < NT) LOAD_A(RA0, RA1, RA2, RA3, t + 2);
            EXPW(RB0, RB1, RB2, RB3, 1, t + 1);
        }
        BAR();
        if (cons) {
            MFMA_TILE(t + 1, 1);
        } else {
            if (t + 3 < NT) LOAD_A(RB0, RB1, RB2, RB3, t + 3);
            if (t + 2 < NT) EXPW(RA0, RA1, RA2, RA3, 0, t + 2);
        }
        BAR();
    }

    if (!cons) {
        s_acc += __shfl_xor(s_acc, 1);
        s_acc += __shfl_xor(s_acc, 2);
        s_acc += __shfl_xor(s_acc, 4);
        if ((lane & 7) == 0) s_part[jc * N + rb + prow] = s_acc;
    } else {
        float* dst = (jc == 0) ? pv0 : pvx;
#pragma unroll
        for (int mt = 0; mt < 4; ++mt)
#pragma unroll
            for (int nt = 0; nt < 2; ++nt)
#pragma unroll
                for (int reg = 0; reg < 4; ++reg) {
                    int row = rb + mt * 16 + q * 4 + reg;
                    int col = (w * 2 + (nt == 1)) * 0 + w * 32 + nt * 16 + r;
                    dst[(size_t)row * CH + col] = acc[mt][nt][reg];
                }
    }
#undef LOAD_A
#undef EXPW
#undef MFMA_TILE
}

// K5: out[i][c] = (pv0 + pvx) * inv(s0 + s1). pv0 lives in d_out.
__global__ __launch_bounds__(256) void k5_reduce(
    const float* __restrict__ pvx, const float* __restrict__ s_part,
    float* __restrict__ out)
{
    int g = blockIdx.x * 256 + threadIdx.x;      // float4 index
    int row = g >> 6;
    float s = s_part[row] + s_part[N + row];
    float inv = (s != 0.f) ? 1.0f / s : 0.f;
    float4* out4 = (float4*)out;
    const float4* p1 = (const float4*)pvx;
    float4 v = out4[g];
    float4 a = p1[g];
    v.x = (v.x + a.x) * inv;
    v.y = (v.y + a.y) * inv;
    v.z = (v.z + a.z) * inv;
    v.w = (v.w + a.w) * inv;
    out4[g] = v;
}

// ================== ABLATION (diagnostic only; writes to scratch) ==========
// v14 structure, role-isolated. V=1: producers only. V=2: consumers only.
// 4 in-kernel repeats for top-5 visibility. Results never validated.
#define AJCW 1024
#define ANS 32
#define APBLK (32 * 512 * 4)

template<int V>
__global__ __launch_bounds__(640, 2) void kabl(
    const int* __restrict__ adj, const float* __restrict__ f1v,
    const float* __restrict__ f2v, const unsigned short* __restrict__ xtp,
    float* __restrict__ part, float* __restrict__ s_part)
{
    __shared__ __align__(16) unsigned short Bbuf[2][16 * 512];
    __shared__ unsigned maskL[256 * 33];
    __shared__ __align__(16) float f2s[AJCW];

    const int tid = threadIdx.x;
    const int bid = blockIdx.x;
    const int jc = bid & 7;
    const int blkRow = bid >> 3;
    const int rb = blkRow * 256;
    const int jbase = jc * AJCW;

    if (tid < 256)
        *(float4*)(&f2s[tid * 4]) = *(const float4*)(f2v + jbase + tid * 4);

    if (tid >= 512) {
        // producers (waves 8,9)
        const int p = tid - 512;
        const int pr = p * 2;
        const int* ap0 = adj + (size_t)(rb + pr) * N + jbase;
        const int* ap1 = ap0 + N;
        unsigned* m0p = &maskL[pr * 33];
        unsigned* m1p = &maskL[(pr + 1) * 33];
        int4 A0[8], A1[8], B0[8], B1[8];
#define PLOAD(X0, X1, tt) { \
        const int4* q0_ = (const int4*)(ap0 + (tt) * 32); \
        const int4* q1_ = (const int4*)(ap1 + (tt) * 32); \
        _Pragma("unroll") for (int e = 0; e < 8; ++e) X0[e] = q0_[e]; \
        _Pragma("unroll") for (int e = 0; e < 8; ++e) X1[e] = q1_[e]; }
#define PCOMP(X0, X1, tt) { \
        unsigned mm0 = 0, mm1 = 0; \
        _Pragma("unroll") for (int e = 0; e < 8; ++e) { \
            mm0 |= ((unsigned)(X0[e].x > 0) << (e * 4)) \
                 | ((unsigned)(X0[e].y > 0) << (e * 4 + 1)) \
                 | ((unsigned)(X0[e].z > 0) << (e * 4 + 2)) \
                 | ((unsigned)(X0[e].w > 0) << (e * 4 + 3)); \
            mm1 |= ((unsigned)(X1[e].x > 0) << (e * 4)) \
                 | ((unsigned)(X1[e].y > 0) << (e * 4 + 1)) \
                 | ((unsigned)(X1[e].z > 0) << (e * 4 + 2)) \
                 | ((unsigned)(X1[e].w > 0) << (e * 4 + 3)); \
        } \
        m0p[tt] = mm0; m1p[tt] = mm1; }
        for (int rep = 0; rep < 4; ++rep) {
            if constexpr (V == 1) {
                PLOAD(A0, A1, 0);
                PLOAD(B0, B1, 1);
                PCOMP(A0, A1, 0);
            }
            __syncthreads();
            for (int t = 0; t < ANS; t += 2) {
                if constexpr (V == 1) {
                    if (t + 2 < ANS) PLOAD(A0, A1, t + 2);
                    PCOMP(B0, B1, t + 1);
                }
                BAR();
                if constexpr (V == 1) {
                    if (t + 3 < ANS) PLOAD(B0, B1, t + 3);
                    if (t + 2 < ANS) PCOMP(A0, A1, t + 2);
                }
                BAR();
            }
            __syncthreads();
        }
#undef PLOAD
#undef PCOMP
    } else {
        // consumers (waves 0-7)
        const int lane = tid & 63;
        const int w = tid >> 6;
        const int r = lane & 15, q = lane >> 4;
        const float f1r0 = f1v[rb + w * 32 + r];
        const float f1r1 = f1v[rb + w * 32 + 16 + r];
        const unsigned short* xsrc0 = xtp + ((size_t)((w * 2 + 0) * 256 + jc * ANS) * 64 + lane) * 8;
        const unsigned short* xsrc1 = xtp + ((size_t)((w * 2 + 1) * 256 + jc * ANS) * 64 + lane) * 8;

        f32x4 acc0[16], acc1[16];
#pragma unroll
        for (int ct = 0; ct < 16; ++ct) {
            acc0[ct] = (f32x4){0.f, 0.f, 0.f, 0.f};
            acc1[ct] = (f32x4){0.f, 0.f, 0.f, 0.f};
        }
        float s0 = 0.f, s1 = 0.f;
        bf16x8 Bs0, Bs1;

        for (int rep = 0; rep < 4; ++rep) {
            if constexpr (V == 2) {
                Bs0 = *(const bf16x8*)(xsrc0);
                Bs1 = *(const bf16x8*)(xsrc1);
                *(bf16x8*)(&Bbuf[0][(w * 2 + 0) * 512 + lane * 8]) = Bs0;
                *(bf16x8*)(&Bbuf[0][(w * 2 + 1) * 512 + lane * 8]) = Bs1;
            }
            __syncthreads();
            for (int t = 0; t < ANS; ++t) {
                if constexpr (V == 2) {
                    if (t + 1 < ANS) {
                        Bs0 = *(const bf16x8*)(xsrc0 + (size_t)(t + 1) * 512);
                        Bs1 = *(const bf16x8*)(xsrc1 + (size_t)(t + 1) * 512);
                    }
                    unsigned w0 = maskL[(w * 32 + r) * 33 + t];
                    unsigned w1 = maskL[(w * 32 + 16 + r) * 33 + t];
                    unsigned bits0 = (w0 >> (q * 8)) & 0xffu;
                    unsigned bits1 = (w1 >> (q * 8)) & 0xffu;
                    float4 g0 = *(const float4*)(&f2s[t * 32 + q * 8]);
                    float4 g1 = *(const float4*)(&f2s[t * 32 + q * 8 + 4]);
                    float gv[8] = {g0.x, g0.y, g0.z, g0.w, g1.x, g1.y, g1.z, g1.w};
                    bf16x8 pka, pkb;
#pragma unroll
                    for (int e = 0; e < 8; ++e) {
                        float ta_ = f1r0 + gv[e];
                        ta_ = fmaxf(ta_, 0.01f * ta_);
                        float pa_ = ((bits0 >> e) & 1u) ? __expf(ta_) : 0.f;
                        s0 += pa_;
                        pka[e] = (__bf16)pa_;
                        float tb_ = f1r1 + gv[e];
                        tb_ = fmaxf(tb_, 0.01f * tb_);
                        float pb_ = ((bits1 >> e) & 1u) ? __expf(tb_) : 0.f;
                        s1 += pb_;
                        pkb[e] = (__bf16)pb_;
                    }
                    const unsigned short* bb = &Bbuf[t & 1][lane * 8];
#pragma unroll
                    for (int ct = 0; ct < 16; ++ct) {
                        bf16x8 Bv = *(const bf16x8*)(bb + ct * 512);
                        acc0[ct] = __builtin_amdgcn_mfma_f32_16x16x32_bf16(pka, Bv, acc0[ct], 0, 0, 0);
                        acc1[ct] = __builtin_amdgcn_mfma_f32_16x16x32_bf16(pkb, Bv, acc1[ct], 0, 0, 0);
                    }
                    if (t + 1 < ANS) {
                        *(bf16x8*)(&Bbuf[(t + 1) & 1][(w * 2 + 0) * 512 + lane * 8]) = Bs0;
                        *(bf16x8*)(&Bbuf[(t + 1) & 1][(w * 2 + 1) * 512 + lane * 8]) = Bs1;
                    }
                }
                BAR();
            }
            __syncthreads();
        }

        if constexpr (V == 2) {
            s0 += __shfl_xor(s0, 16); s0 += __shfl_xor(s0, 32);
            s1 += __shfl_xor(s1, 16); s1 += __shfl_xor(s1, 32);
            if (lane < 16) {
                s_part[(size_t)jc * N + rb + w * 32 + lane] = s0;
                s_part[(size_t)jc * N + rb + w * 32 + 16 + lane] = s1;
            }
            float* pb = part + (size_t)(blkRow * 8 + jc) * APBLK;
#pragma unroll
            for (int ct = 0; ct < 16; ++ct) {
                *(f32x4*)(pb + ((size_t)(ct * 2 + 0) * 512 + tid) * 4) = acc0[ct];
                *(f32x4*)(pb + ((size_t)(ct * 2 + 1) * 512 + tid) * 4) = acc1[ct];
            }
        }
    }
}

extern "C" void kernel_launch(void* const* d_in, const int* in_sizes, int n_in,
                              void* d_out, int out_size, void* d_ws, size_t ws_size,
                              hipStream_t stream)
{
    const float* inlayer = (const float*)d_in[0];
    const int*   adj     = (const int*)d_in[1];
    const float* W       = (const float*)d_in[2];
    const float* w1      = (const float*)d_in[3];
    const float* b1      = (const float*)d_in[4];
    const float* w2      = (const float*)d_in[5];
    const float* b2      = (const float*)d_in[6];
    float* out = (float*)d_out;

    char* ws = (char*)d_ws;
    float* p1 = (float*)(ws + OFF_P1);
    float* p2 = (float*)(ws + OFF_P2);
    float* t1 = (float*)(ws + OFF_T1);
    float* t2 = (float*)(ws + OFF_T2);
    float* f1 = (float*)(ws + OFF_F1);
    float* f2 = (float*)(ws + OFF_F2);
    unsigned short* xtp = (unsigned short*)(ws + OFF_XT);
    float* s_part = (float*)(ws + OFF_SP);
    float* pvx = (float*)(ws + OFF_PV);
    float* ab_part = (float*)(ws + OFF_AB_PART);
    float* ab_s    = (float*)(ws + OFF_AB_S);

    // ---- real pipeline (R9, best known) ----
    k1a<<<dim3(32), dim3(256), 0, stream>>>(W, w1, w2, p1, p2);
    k1b<<<dim3(1), dim3(256), 0, stream>>>(p1, p2, t1, t2);
    ktf<<<dim3(N / 32), dim3(256), 0, stream>>>(
        inlayer, t1, t2, b1, b2, xtp, f1, f2);
    k34_fused<<<dim3((N / BM) * NJC), dim3(1024), 0, stream>>>(
        adj, f1, f2, xtp, out, pvx, s_part);
    k5_reduce<<<dim3(N * CH / 4 / 256), dim3(256), 0, stream>>>(pvx, s_part, out);

    // ---- diagnostics (scratch only) ----
    kabl<1><<<dim3((N / 256) * 8), dim3(640), 0, stream>>>(
        adj, f1, f2, xtp, ab_part, ab_s);
    kabl<2><<<dim3((N / 256) * 8), dim3(640), 0, stream>>>(
        adj, f1, f2, xtp, ab_part, ab_s);
}

// Round 16
// 358.709 us; speedup vs baseline: 1.6565x; 1.6565x over previous
//
#include <hip/hip_runtime.h>
#include <hip/hip_bf16.h>

typedef float f32x4 __attribute__((ext_vector_type(4)));
typedef __bf16 bf16x8 __attribute__((ext_vector_type(8)));

#define N 8192
#define CH 256
#define NJC 4            // j-chunks
#define JCW (N / NJC)    // 2048 j per chunk
#define JT 128           // j per tile
#define NT (JCW / JT)    // 16 tiles per chunk
#define BM 64            // rows per block

// ---- workspace layout (bytes) ----
static constexpr size_t OFF_P1 = 0;
static constexpr size_t OFF_P2 = 32768;
static constexpr size_t OFF_T1 = 65536;
static constexpr size_t OFF_T2 = 66560;
static constexpr size_t OFF_E1 = 67584;                        // e^{f1}, N f32
static constexpr size_t OFF_G1 = OFF_E1 + (size_t)N * 4;       // e^{.01 f1}
static constexpr size_t OFF_E2 = OFF_G1 + (size_t)N * 4;       // e^{f2}
static constexpr size_t OFF_G2 = OFF_E2 + (size_t)N * 4;       // e^{.01 f2}
static constexpr size_t OFF_XT = 262144;                       // packed B, 4 MB
static constexpr size_t OFF_SP = OFF_XT + (size_t)CH * N * 2;  // 4x8192 f32
static constexpr size_t OFF_PV = OFF_SP + (size_t)NJC * N * 4; // 3x8 MB

// K1a: partial t-vectors over h-slices of 8.
__global__ __launch_bounds__(256) void k1a(
    const float* __restrict__ W, const float* __restrict__ w1,
    const float* __restrict__ w2, float* __restrict__ p1, float* __restrict__ p2)
{
    int b = blockIdx.x, c = threadIdx.x;
    float a1 = 0.f, a2 = 0.f;
#pragma unroll
    for (int hh = 0; hh < 8; ++hh) {
        int h = b * 8 + hh;
        float wv = W[h * CH + c];
        a1 = __builtin_fmaf(w1[h], wv, a1);
        a2 = __builtin_fmaf(w2[h], wv, a2);
    }
    p1[b * CH + c] = a1;
    p2[b * CH + c] = a2;
}

// K1b: fold 32 partials -> t1,t2.
__global__ __launch_bounds__(256) void k1b(
    const float* __restrict__ p1, const float* __restrict__ p2,
    float* __restrict__ t1, float* __restrict__ t2)
{
    int c = threadIdx.x;
    float a1 = 0.f, a2 = 0.f;
#pragma unroll 8
    for (int b = 0; b < 32; ++b) { a1 += p1[b * CH + c]; a2 += p2[b * CH + c]; }
    t1[c] = a1;
    t2[c] = a2;
}

// KTF: fused pack + rank-1 softmax factors. inlayer -> xtp (fragment-packed
// bf16) and per-row E1=e^{f1}, G1=e^{.01 f1}; per-col E2=e^{f2}, G2=e^{.01 f2}.
__global__ __launch_bounds__(256) void ktf(
    const float* __restrict__ x, const float* __restrict__ t1,
    const float* __restrict__ t2, const float* __restrict__ b1,
    const float* __restrict__ b2, unsigned short* __restrict__ xtp,
    float* __restrict__ E1g, float* __restrict__ G1g,
    float* __restrict__ E2g, float* __restrict__ G2g)
{
    __shared__ unsigned short tile[32][264];     // +8 pad
    int js32 = blockIdx.x;
    int jb = js32 * 32;
    int t = threadIdx.x;
    int lane = t & 63;
    int wv = t >> 6;
    const float4* t1v = (const float4*)t1;
    const float4* t2v = (const float4*)t2;
    float4 ta = t1v[lane], tb = t2v[lane];
    float bb1 = b1[0], bb2 = b2[0];
#pragma unroll
    for (int it = 0; it < 8; ++it) {
        int jr = it * 4 + wv;
        float4 v = *(const float4*)(x + (size_t)(jb + jr) * CH + lane * 4);
        __hip_bfloat16 h0 = __float2bfloat16(v.x);
        __hip_bfloat16 h1 = __float2bfloat16(v.y);
        __hip_bfloat16 h2 = __float2bfloat16(v.z);
        __hip_bfloat16 h3 = __float2bfloat16(v.w);
        tile[jr][lane * 4 + 0] = *(unsigned short*)&h0;
        tile[jr][lane * 4 + 1] = *(unsigned short*)&h1;
        tile[jr][lane * 4 + 2] = *(unsigned short*)&h2;
        tile[jr][lane * 4 + 3] = *(unsigned short*)&h3;
        float d1 = v.x * ta.x + v.y * ta.y + v.z * ta.z + v.w * ta.w;
        float d2 = v.x * tb.x + v.y * tb.y + v.z * tb.z + v.w * tb.w;
#pragma unroll
        for (int off = 32; off; off >>= 1) {
            d1 += __shfl_down(d1, off);
            d2 += __shfl_down(d2, off);
        }
        if (lane == 0) {
            float f1 = d1 + bb1, f2 = d2 + bb2;
            E1g[jb + jr] = __expf(f1);
            G1g[jb + jr] = __expf(0.01f * f1);
            E2g[jb + jr] = __expf(f2);
            G2g[jb + jr] = __expf(0.01f * f2);
        }
    }
    __syncthreads();
    int r = lane & 15, q = lane >> 4;
#pragma unroll
    for (int pass = 0; pass < 4; ++pass) {
        int ct = pass * 4 + wv;
        unsigned short vs[8];
#pragma unroll
        for (int e = 0; e < 8; ++e) vs[e] = tile[q * 8 + e][ct * 16 + r];
        size_t u = ((size_t)ct * 256 + js32) * 64 + lane;
        *(ulonglong2*)(xtp + u * 8) = *(ulonglong2*)vs;
    }
}

// Raw barrier: LDS visibility only; global loads stay in flight per-wave.
#define BAR() { asm volatile("s_waitcnt lgkmcnt(0)" ::: "memory"); \
                __builtin_amdgcn_s_barrier(); }

// K34 v15 = R9 skeleton + rank-1 P-gen + 2 blocks/CU.
// 1024 threads = 16 waves. Waves 0-7: consumers (MFMA + B loads only).
// Waves 8-15: producers (adj depth-2 prefetch + rank-1 P + LDS write).
// BM=64 rows x 2048-j chunk (NJC=4), JT=128, NT=16, grid 512 (2 blocks/CU).
// P double-buffered LDS, XOR-swizzled unit = row*16 + (slot ^ (row&7)).
// P[i][j] = m_ij * (E1_i*E2_j > 1 ? E1_i*E2_j : G1_i*G2_j)  — no exp in loop.
__global__ __launch_bounds__(1024, 8) void k34_fused(
    const int* __restrict__ adj, const float* __restrict__ E1g,
    const float* __restrict__ G1g, const float* __restrict__ E2g,
    const float* __restrict__ G2g, const unsigned short* __restrict__ xtp,
    float* __restrict__ pv0, float* __restrict__ pvx, float* __restrict__ s_part)
{
    __shared__ __align__(16) unsigned short P[2][BM * JT];   // 2 x 16 KB
    __shared__ __align__(16) float e2s[JCW];                 // 8 KB
    __shared__ __align__(16) float g2s[JCW];                 // 8 KB

    const int tid = threadIdx.x;
    const int lane = tid & 63;
    const int w = tid >> 6;              // wave 0..15
    const int r = lane & 15, q = lane >> 4;
    const int bid = blockIdx.x;
    const int jc = bid & 3;              // j-chunk
    const int rb = (bid >> 2) * BM;
    const int jbase = jc * JCW;
    const bool cons = (w < 8);

    const int ptid = tid - 512;
    const int prow = (ptid >> 3) & 63;
    const int pjo = (ptid & 7) * 16;
    const int* aptr = adj + (size_t)(rb + prow) * N + jbase + pjo;
    const int s0i = (ptid & 7) * 2;
    const int wu0 = prow * 16 + (s0i ^ (prow & 7));
    const int wu1 = prow * 16 + ((s0i + 1) ^ (prow & 7));
    float E1r = 0.f, G1r = 0.f;
    if (!cons) { E1r = E1g[rb + prow]; G1r = G1g[rb + prow]; }

    const unsigned short* xb0 = xtp + (((size_t)(w * 2) * 256 + jc * (JCW / 32)) * 64 + lane) * 8;
    const unsigned short* xb1 = xtp + (((size_t)(w * 2 + 1) * 256 + jc * (JCW / 32)) * 64 + lane) * 8;

    f32x4 acc[4][2];
#pragma unroll
    for (int mt = 0; mt < 4; ++mt)
#pragma unroll
        for (int nt = 0; nt < 2; ++nt) acc[mt][nt] = (f32x4){0.f, 0.f, 0.f, 0.f};
    float s_acc = 0.f;

    int4 RA0, RA1, RA2, RA3, RB0, RB1, RB2, RB3;

#define LOAD_A(R0, R1, R2, R3, t)                                   \
    { const int4* p_ = (const int4*)(aptr + (size_t)(t) * JT);      \
      R0 = p_[0]; R1 = p_[1]; R2 = p_[2]; R3 = p_[3]; }
#define EXPW(R0, R1, R2, R3, buf, tt)                               \
    { float4 g0 = *(const float4*)(&e2s[(tt) * JT + pjo]);          \
      float4 g1 = *(const float4*)(&e2s[(tt) * JT + pjo + 4]);      \
      float4 g2 = *(const float4*)(&e2s[(tt) * JT + pjo + 8]);      \
      float4 g3 = *(const float4*)(&e2s[(tt) * JT + pjo + 12]);     \
      float4 h0 = *(const float4*)(&g2s[(tt) * JT + pjo]);          \
      float4 h1 = *(const float4*)(&g2s[(tt) * JT + pjo + 4]);      \
      float4 h2 = *(const float4*)(&g2s[(tt) * JT + pjo + 8]);      \
      float4 h3 = *(const float4*)(&g2s[(tt) * JT + pjo + 12]);     \
      int av[16] = {R0.x, R0.y, R0.z, R0.w, R1.x, R1.y, R1.z, R1.w, \
                    R2.x, R2.y, R2.z, R2.w, R3.x, R3.y, R3.z, R3.w};\
      float gv[16] = {g0.x, g0.y, g0.z, g0.w, g1.x, g1.y, g1.z, g1.w,\
                      g2.x, g2.y, g2.z, g2.w, g3.x, g3.y, g3.z, g3.w};\
      float hv[16] = {h0.x, h0.y, h0.z, h0.w, h1.x, h1.y, h1.z, h1.w,\
                      h2.x, h2.y, h2.z, h2.w, h3.x, h3.y, h3.z, h3.w};\
      bf16x8 pk0, pk1;                                              \
      _Pragma("unroll")                                             \
      for (int e = 0; e < 16; ++e) {                                \
          float te = E1r * gv[e];                                   \
          float tf = G1r * hv[e];                                   \
          float p_ = (te > 1.0f) ? te : tf;                         \
          p_ = (av[e] > 0) ? p_ : 0.f;                              \
          s_acc += p_;                                              \
          if (e < 8) pk0[e] = (__bf16)p_; else pk1[e - 8] = (__bf16)p_; \
      }                                                             \
      *reinterpret_cast<bf16x8*>(&P[buf][(size_t)wu0 * 8]) = pk0;   \
      *reinterpret_cast<bf16x8*>(&P[buf][(size_t)wu1 * 8]) = pk1; }
#define MFMA_TILE(tt, buf)                                          \
    { _Pragma("unroll")                                             \
      for (int kk = 0; kk < 4; ++kk) {                              \
          bf16x8 B0 = *(const bf16x8*)(xb0 + ((size_t)((tt) * 4 + kk) * 64) * 8); \
          bf16x8 B1 = *(const bf16x8*)(xb1 + ((size_t)((tt) * 4 + kk) * 64) * 8); \
          _Pragma("unroll")                                         \
          for (int mt = 0; mt < 4; ++mt) {                          \
              int u_ = (mt * 16 + r) * 16 + ((kk * 4 + q) ^ (r & 7)); \
              bf16x8 A = *(const bf16x8*)(&P[buf][(size_t)u_ * 8]); \
              acc[mt][0] = __builtin_amdgcn_mfma_f32_16x16x32_bf16(A, B0, acc[mt][0], 0, 0, 0); \
              acc[mt][1] = __builtin_amdgcn_mfma_f32_16x16x32_bf16(A, B1, acc[mt][1], 0, 0, 0); \
          }                                                         \
      } }

    // stage E2/G2 chunk into LDS (1024 threads x 2 floats each)
    *(float2*)(&e2s[tid * 2]) = *(const float2*)(E2g + jbase + tid * 2);
    *(float2*)(&g2s[tid * 2]) = *(const float2*)(G2g + jbase + tid * 2);

    if (!cons) {
        LOAD_A(RA0, RA1, RA2, RA3, 0);
        LOAD_A(RB0, RB1, RB2, RB3, 1);
    }
    __syncthreads();                      // e2s/g2s staged (full drain once)
    if (!cons) EXPW(RA0, RA1, RA2, RA3, 0, 0);
    BAR();                                // P[0] ready

    for (int t = 0; t < NT; t += 2) {
        if (cons) {
            MFMA_TILE(t, 0);
        } else {
            if (t + 2 < NT) LOAD_A(RA0, RA1, RA2, RA3, t + 2);
            EXPW(RB0, RB1, RB2, RB3, 1, t + 1);
        }
        BAR();
        if (cons) {
            MFMA_TILE(t + 1, 1);
        } else {
            if (t + 3 < NT) LOAD_A(RB0, RB1, RB2, RB3, t + 3);
            if (t + 2 < NT) EXPW(RA0, RA1, RA2, RA3, 0, t + 2);
        }
        BAR();
    }

    if (!cons) {
        // row-sum partial: 8 producer threads per row (consecutive lanes)
        s_acc += __shfl_xor(s_acc, 1);
        s_acc += __shfl_xor(s_acc, 2);
        s_acc += __shfl_xor(s_acc, 4);
        if ((lane & 7) == 0) s_part[jc * N + rb + prow] = s_acc;
    } else {
        // write PV partial. D layout: col = lane&15, row = (lane>>4)*4 + reg
        float* dst = (jc == 0) ? pv0 : (pvx + (size_t)(jc - 1) * N * CH);
#pragma unroll
        for (int mt = 0; mt < 4; ++mt)
#pragma unroll
            for (int nt = 0; nt < 2; ++nt)
#pragma unroll
                for (int reg = 0; reg < 4; ++reg) {
                    int row = rb + mt * 16 + q * 4 + reg;
                    int col = w * 32 + nt * 16 + r;
                    dst[(size_t)row * CH + col] = acc[mt][nt][reg];
                }
    }
#undef LOAD_A
#undef EXPW
#undef MFMA_TILE
}

// K5: out[i][c] = (sum_k pv_k) * inv(sum_k s_k). pv0 lives in d_out.
__global__ __launch_bounds__(256) void k5_reduce(
    const float* __restrict__ pvx, const float* __restrict__ s_part,
    float* __restrict__ out)
{
    int g = blockIdx.x * 256 + threadIdx.x;      // float4 index
    int row = g >> 6;
    float s = s_part[row] + s_part[N + row] + s_part[2 * N + row] + s_part[3 * N + row];
    float inv = (s != 0.f) ? 1.0f / s : 0.f;
    float4* out4 = (float4*)out;
    const float4* p1 = (const float4*)pvx;
    const float4* p2 = p1 + (size_t)N * CH / 4;
    const float4* p3 = p2 + (size_t)N * CH / 4;
    float4 v = out4[g];
    float4 a = p1[g], b = p2[g], c = p3[g];
    v.x = (v.x + a.x + b.x + c.x) * inv;
    v.y = (v.y + a.y + b.y + c.y) * inv;
    v.z = (v.z + a.z + b.z + c.z) * inv;
    v.w = (v.w + a.w + b.w + c.w) * inv;
    out4[g] = v;
}

extern "C" void kernel_launch(void* const* d_in, const int* in_sizes, int n_in,
                              void* d_out, int out_size, void* d_ws, size_t ws_size,
                              hipStream_t stream)
{
    const float* inlayer = (const float*)d_in[0];
    const int*   adj     = (const int*)d_in[1];
    const float* W       = (const float*)d_in[2];
    const float* w1      = (const float*)d_in[3];
    const float* b1      = (const float*)d_in[4];
    const float* w2      = (const float*)d_in[5];
    const float* b2      = (const float*)d_in[6];
    float* out = (float*)d_out;

    char* ws = (char*)d_ws;
    float* p1 = (float*)(ws + OFF_P1);
    float* p2 = (float*)(ws + OFF_P2);
    float* t1 = (float*)(ws + OFF_T1);
    float* t2 = (float*)(ws + OFF_T2);
    float* E1g = (float*)(ws + OFF_E1);
    float* G1g = (float*)(ws + OFF_G1);
    float* E2g = (float*)(ws + OFF_E2);
    float* G2g = (float*)(ws + OFF_G2);
    unsigned short* xtp = (unsigned short*)(ws + OFF_XT);
    float* s_part = (float*)(ws + OFF_SP);
    float* pvx = (float*)(ws + OFF_PV);

    k1a<<<dim3(32), dim3(256), 0, stream>>>(W, w1, w2, p1, p2);
    k1b<<<dim3(1), dim3(256), 0, stream>>>(p1, p2, t1, t2);
    ktf<<<dim3(N / 32), dim3(256), 0, stream>>>(
        inlayer, t1, t2, b1, b2, xtp, E1g, G1g, E2g, G2g);
    k34_fused<<<dim3((N / BM) * NJC), dim3(1024), 0, stream>>>(
        adj, E1g, G1g, E2g, G2g, xtp, out, pvx, s_part);
    k5_reduce<<<dim3(N * CH / 4 / 256), dim3(256), 0, stream>>>(pvx, s_part, out);
}

// Round 17
// 109.200 us; speedup vs baseline: 5.4414x; 3.2849x over previous
//
#include <hip/hip_runtime.h>
#include <hip/hip_bf16.h>

typedef float f32x4 __attribute__((ext_vector_type(4)));
typedef __bf16 bf16x8 __attribute__((ext_vector_type(8)));

#define N 8192
#define CH 256
#define NJC 2            // j-chunks
#define JCW (N / NJC)    // 4096 j per chunk
#define JT 128           // j per tile
#define NT (JCW / JT)    // 32 tiles per chunk
#define BM 64            // rows per block

// ---- workspace layout (bytes) ----
static constexpr size_t OFF_P1 = 0;
static constexpr size_t OFF_P2 = 32768;
static constexpr size_t OFF_T1 = 65536;
static constexpr size_t OFF_T2 = 66560;
static constexpr size_t OFF_E1 = 67584;                        // e^{f1}, N f32
static constexpr size_t OFF_G1 = OFF_E1 + (size_t)N * 4;       // e^{.01 f1}
static constexpr size_t OFF_E2 = OFF_G1 + (size_t)N * 4;       // e^{f2}
static constexpr size_t OFF_G2 = OFF_E2 + (size_t)N * 4;       // e^{.01 f2}
static constexpr size_t OFF_XT = 262144;                       // packed B, 4 MB
static constexpr size_t OFF_SP = OFF_XT + (size_t)CH * N * 2;  // 2x8192 f32
static constexpr size_t OFF_PV = OFF_SP + (size_t)NJC * N * 4; // 1x8 MB

// K1a: partial t-vectors over h-slices of 8.
__global__ __launch_bounds__(256) void k1a(
    const float* __restrict__ W, const float* __restrict__ w1,
    const float* __restrict__ w2, float* __restrict__ p1, float* __restrict__ p2)
{
    int b = blockIdx.x, c = threadIdx.x;
    float a1 = 0.f, a2 = 0.f;
#pragma unroll
    for (int hh = 0; hh < 8; ++hh) {
        int h = b * 8 + hh;
        float wv = W[h * CH + c];
        a1 = __builtin_fmaf(w1[h], wv, a1);
        a2 = __builtin_fmaf(w2[h], wv, a2);
    }
    p1[b * CH + c] = a1;
    p2[b * CH + c] = a2;
}

// K1b: fold 32 partials -> t1,t2.
__global__ __launch_bounds__(256) void k1b(
    const float* __restrict__ p1, const float* __restrict__ p2,
    float* __restrict__ t1, float* __restrict__ t2)
{
    int c = threadIdx.x;
    float a1 = 0.f, a2 = 0.f;
#pragma unroll 8
    for (int b = 0; b < 32; ++b) { a1 += p1[b * CH + c]; a2 += p2[b * CH + c]; }
    t1[c] = a1;
    t2[c] = a2;
}

// KTF: fused pack + rank-1 softmax factors. inlayer -> xtp (fragment-packed
// bf16) and per-row E1=e^{f1}, G1=e^{.01 f1}; per-col E2=e^{f2}, G2=e^{.01 f2}.
__global__ __launch_bounds__(256) void ktf(
    const float* __restrict__ x, const float* __restrict__ t1,
    const float* __restrict__ t2, const float* __restrict__ b1,
    const float* __restrict__ b2, unsigned short* __restrict__ xtp,
    float* __restrict__ E1g, float* __restrict__ G1g,
    float* __restrict__ E2g, float* __restrict__ G2g)
{
    __shared__ unsigned short tile[32][264];     // +8 pad
    int js32 = blockIdx.x;
    int jb = js32 * 32;
    int t = threadIdx.x;
    int lane = t & 63;
    int wv = t >> 6;
    const float4* t1v = (const float4*)t1;
    const float4* t2v = (const float4*)t2;
    float4 ta = t1v[lane], tb = t2v[lane];
    float bb1 = b1[0], bb2 = b2[0];
#pragma unroll
    for (int it = 0; it < 8; ++it) {
        int jr = it * 4 + wv;
        float4 v = *(const float4*)(x + (size_t)(jb + jr) * CH + lane * 4);
        __hip_bfloat16 h0 = __float2bfloat16(v.x);
        __hip_bfloat16 h1 = __float2bfloat16(v.y);
        __hip_bfloat16 h2 = __float2bfloat16(v.z);
        __hip_bfloat16 h3 = __float2bfloat16(v.w);
        tile[jr][lane * 4 + 0] = *(unsigned short*)&h0;
        tile[jr][lane * 4 + 1] = *(unsigned short*)&h1;
        tile[jr][lane * 4 + 2] = *(unsigned short*)&h2;
        tile[jr][lane * 4 + 3] = *(unsigned short*)&h3;
        float d1 = v.x * ta.x + v.y * ta.y + v.z * ta.z + v.w * ta.w;
        float d2 = v.x * tb.x + v.y * tb.y + v.z * tb.z + v.w * tb.w;
#pragma unroll
        for (int off = 32; off; off >>= 1) {
            d1 += __shfl_down(d1, off);
            d2 += __shfl_down(d2, off);
        }
        if (lane == 0) {
            float f1 = d1 + bb1, f2 = d2 + bb2;
            E1g[jb + jr] = __expf(f1);
            G1g[jb + jr] = __expf(0.01f * f1);
            E2g[jb + jr] = __expf(f2);
            G2g[jb + jr] = __expf(0.01f * f2);
        }
    }
    __syncthreads();
    int r = lane & 15, q = lane >> 4;
#pragma unroll
    for (int pass = 0; pass < 4; ++pass) {
        int ct = pass * 4 + wv;
        unsigned short vs[8];
#pragma unroll
        for (int e = 0; e < 8; ++e) vs[e] = tile[q * 8 + e][ct * 16 + r];
        size_t u = ((size_t)ct * 256 + js32) * 64 + lane;
        *(ulonglong2*)(xtp + u * 8) = *(ulonglong2*)vs;
    }
}

// Raw barrier: LDS visibility only; global loads stay in flight per-wave.
#define BAR() { asm volatile("s_waitcnt lgkmcnt(0)" ::: "memory"); \
                __builtin_amdgcn_s_barrier(); }

// K34 v17 = R9 skeleton (launch_bounds(1024,4), NJC=2) + rank-1 P-gen.
// 1024 threads = 16 waves. Waves 0-7: consumers (MFMA + B loads only).
// Waves 8-15: producers (adj depth-2 prefetch + rank-1 P + LDS write).
// P[i][j] = m_ij * (E1_i*E2_j > 1 ? E1_i*E2_j : G1_i*G2_j) — no exp in loop.
__global__ __launch_bounds__(1024, 4) void k34_fused(
    const int* __restrict__ adj, const float* __restrict__ E1g,
    const float* __restrict__ G1g, const float* __restrict__ E2g,
    const float* __restrict__ G2g, const unsigned short* __restrict__ xtp,
    float* __restrict__ pv0, float* __restrict__ pvx, float* __restrict__ s_part)
{
    __shared__ __align__(16) unsigned short P[2][BM * JT];   // 2 x 16 KB
    __shared__ __align__(16) float e2s[JCW];                 // 16 KB
    __shared__ __align__(16) float g2s[JCW];                 // 16 KB

    const int tid = threadIdx.x;
    const int lane = tid & 63;
    const int w = tid >> 6;              // wave 0..15
    const int r = lane & 15, q = lane >> 4;
    const int bid = blockIdx.x;
    const int jc = bid & 1;              // j-chunk
    const int rb = (bid >> 1) * BM;
    const int jbase = jc * JCW;
    const bool cons = (w < 8);

    const int ptid = tid - 512;
    const int prow = (ptid >> 3) & 63;
    const int pjo = (ptid & 7) * 16;
    const int* aptr = adj + (size_t)(rb + prow) * N + jbase + pjo;
    const int s0i = (ptid & 7) * 2;
    const int wu0 = prow * 16 + (s0i ^ (prow & 7));
    const int wu1 = prow * 16 + ((s0i + 1) ^ (prow & 7));
    float E1r = 0.f, G1r = 0.f;
    if (!cons) { E1r = E1g[rb + prow]; G1r = G1g[rb + prow]; }

    const unsigned short* xb0 = xtp + (((size_t)(w * 2) * 256 + jc * (JCW / 32)) * 64 + lane) * 8;
    const unsigned short* xb1 = xtp + (((size_t)(w * 2 + 1) * 256 + jc * (JCW / 32)) * 64 + lane) * 8;

    f32x4 acc[4][2];
#pragma unroll
    for (int mt = 0; mt < 4; ++mt)
#pragma unroll
        for (int nt = 0; nt < 2; ++nt) acc[mt][nt] = (f32x4){0.f, 0.f, 0.f, 0.f};
    float s_acc = 0.f;

    int4 RA0, RA1, RA2, RA3, RB0, RB1, RB2, RB3;

#define LOAD_A(R0, R1, R2, R3, t)                                   \
    { const int4* p_ = (const int4*)(aptr + (size_t)(t) * JT);      \
      R0 = p_[0]; R1 = p_[1]; R2 = p_[2]; R3 = p_[3]; }
#define EXPW(R0, R1, R2, R3, buf, tt)                               \
    { float4 g0 = *(const float4*)(&e2s[(tt) * JT + pjo]);          \
      float4 g1 = *(const float4*)(&e2s[(tt) * JT + pjo + 4]);      \
      float4 g2 = *(const float4*)(&e2s[(tt) * JT + pjo + 8]);      \
      float4 g3 = *(const float4*)(&e2s[(tt) * JT + pjo + 12]);     \
      float4 h0 = *(const float4*)(&g2s[(tt) * JT + pjo]);          \
      float4 h1 = *(const float4*)(&g2s[(tt) * JT + pjo + 4]);      \
      float4 h2 = *(const float4*)(&g2s[(tt) * JT + pjo + 8]);      \
      float4 h3 = *(const float4*)(&g2s[(tt) * JT + pjo + 12]);     \
      int av[16] = {R0.x, R0.y, R0.z, R0.w, R1.x, R1.y, R1.z, R1.w, \
                    R2.x, R2.y, R2.z, R2.w, R3.x, R3.y, R3.z, R3.w};\
      float gv[16] = {g0.x, g0.y, g0.z, g0.w, g1.x, g1.y, g1.z, g1.w,\
                      g2.x, g2.y, g2.z, g2.w, g3.x, g3.y, g3.z, g3.w};\
      float hv[16] = {h0.x, h0.y, h0.z, h0.w, h1.x, h1.y, h1.z, h1.w,\
                      h2.x, h2.y, h2.z, h2.w, h3.x, h3.y, h3.z, h3.w};\
      bf16x8 pk0, pk1;                                              \
      _Pragma("unroll")                                             \
      for (int e = 0; e < 16; ++e) {                                \
          float te = E1r * gv[e];                                   \
          float tf = G1r * hv[e];                                   \
          float p_ = (te > 1.0f) ? te : tf;                         \
          p_ = (av[e] > 0) ? p_ : 0.f;                              \
          s_acc += p_;                                              \
          if (e < 8) pk0[e] = (__bf16)p_; else pk1[e - 8] = (__bf16)p_; \
      }                                                             \
      *reinterpret_cast<bf16x8*>(&P[buf][(size_t)wu0 * 8]) = pk0;   \
      *reinterpret_cast<bf16x8*>(&P[buf][(size_t)wu1 * 8]) = pk1; }
#define MFMA_TILE(tt, buf)                                          \
    { _Pragma("unroll")                                             \
      for (int kk = 0; kk < 4; ++kk) {                              \
          bf16x8 B0 = *(const bf16x8*)(xb0 + ((size_t)((tt) * 4 + kk) * 64) * 8); \
          bf16x8 B1 = *(const bf16x8*)(xb1 + ((size_t)((tt) * 4 + kk) * 64) * 8); \
          _Pragma("unroll")                                         \
          for (int mt = 0; mt < 4; ++mt) {                          \
              int u_ = (mt * 16 + r) * 16 + ((kk * 4 + q) ^ (r & 7)); \
              bf16x8 A = *(const bf16x8*)(&P[buf][(size_t)u_ * 8]); \
              acc[mt][0] = __builtin_amdgcn_mfma_f32_16x16x32_bf16(A, B0, acc[mt][0], 0, 0, 0); \
              acc[mt][1] = __builtin_amdgcn_mfma_f32_16x16x32_bf16(A, B1, acc[mt][1], 0, 0, 0); \
          }                                                         \
      } }

    // stage E2/G2 chunk into LDS (1024 threads x 4 floats each)
    *(float4*)(&e2s[tid * 4]) = *(const float4*)(E2g + jbase + tid * 4);
    *(float4*)(&g2s[tid * 4]) = *(const float4*)(G2g + jbase + tid * 4);

    if (!cons) {
        LOAD_A(RA0, RA1, RA2, RA3, 0);
        LOAD_A(RB0, RB1, RB2, RB3, 1);
    }
    __syncthreads();                      // e2s/g2s staged (full drain once)
    if (!cons) EXPW(RA0, RA1, RA2, RA3, 0, 0);
    BAR();                                // P[0] ready

    for (int t = 0; t < NT; t += 2) {
        if (cons) {
            MFMA_TILE(t, 0);
        } else {
            if (t + 2 < NT) LOAD_A(RA0, RA1, RA2, RA3, t + 2);
            EXPW(RB0, RB1, RB2, RB3, 1, t + 1);
        }
        BAR();
        if (cons) {
            MFMA_TILE(t + 1, 1);
        } else {
            if (t + 3 < NT) LOAD_A(RB0, RB1, RB2, RB3, t + 3);
            if (t + 2 < NT) EXPW(RA0, RA1, RA2, RA3, 0, t + 2);
        }
        BAR();
    }

    if (!cons) {
        // row-sum partial: 8 producer threads per row (consecutive lanes)
        s_acc += __shfl_xor(s_acc, 1);
        s_acc += __shfl_xor(s_acc, 2);
        s_acc += __shfl_xor(s_acc, 4);
        if ((lane & 7) == 0) s_part[jc * N + rb + prow] = s_acc;
    } else {
        // write PV partial. D layout: col = lane&15, row = (lane>>4)*4 + reg
        float* dst = (jc == 0) ? pv0 : pvx;
#pragma unroll
        for (int mt = 0; mt < 4; ++mt)
#pragma unroll
            for (int nt = 0; nt < 2; ++nt)
#pragma unroll
                for (int reg = 0; reg < 4; ++reg) {
                    int row = rb + mt * 16 + q * 4 + reg;
                    int col = w * 32 + nt * 16 + r;
                    dst[(size_t)row * CH + col] = acc[mt][nt][reg];
                }
    }
#undef LOAD_A
#undef EXPW
#undef MFMA_TILE
}

// K5: out[i][c] = (pv0 + pvx) * inv(s0 + s1). pv0 lives in d_out.
__global__ __launch_bounds__(256) void k5_reduce(
    const float* __restrict__ pvx, const float* __restrict__ s_part,
    float* __restrict__ out)
{
    int g = blockIdx.x * 256 + threadIdx.x;      // float4 index
    int row = g >> 6;
    float s = s_part[row] + s_part[N + row];
    float inv = (s != 0.f) ? 1.0f / s : 0.f;
    float4* out4 = (float4*)out;
    const float4* p1 = (const float4*)pvx;
    float4 v = out4[g];
    float4 a = p1[g];
    v.x = (v.x + a.x) * inv;
    v.y = (v.y + a.y) * inv;
    v.z = (v.z + a.z) * inv;
    v.w = (v.w + a.w) * inv;
    out4[g] = v;
}

extern "C" void kernel_launch(void* const* d_in, const int* in_sizes, int n_in,
                              void* d_out, int out_size, void* d_ws, size_t ws_size,
                              hipStream_t stream)
{
    const float* inlayer = (const float*)d_in[0];
    const int*   adj     = (const int*)d_in[1];
    const float* W       = (const float*)d_in[2];
    const float* w1      = (const float*)d_in[3];
    const float* b1      = (const float*)d_in[4];
    const float* w2      = (const float*)d_in[5];
    const float* b2      = (const float*)d_in[6];
    float* out = (float*)d_out;

    char* ws = (char*)d_ws;
    float* p1 = (float*)(ws + OFF_P1);
    float* p2 = (float*)(ws + OFF_P2);
    float* t1 = (float*)(ws + OFF_T1);
    float* t2 = (float*)(ws + OFF_T2);
    float* E1g = (float*)(ws + OFF_E1);
    float* G1g = (float*)(ws + OFF_G1);
    float* E2g = (float*)(ws + OFF_E2);
    float* G2g = (float*)(ws + OFF_G2);
    unsigned short* xtp = (unsigned short*)(ws + OFF_XT);
    float* s_part = (float*)(ws + OFF_SP);
    float* pvx = (float*)(ws + OFF_PV);

    k1a<<<dim3(32), dim3(256), 0, stream>>>(W, w1, w2, p1, p2);
    k1b<<<dim3(1), dim3(256), 0, stream>>>(p1, p2, t1, t2);
    ktf<<<dim3(N / 32), dim3(256), 0, stream>>>(
        inlayer, t1, t2, b1, b2, xtp, E1g, G1g, E2g, G2g);
    k34_fused<<<dim3((N / BM) * NJC), dim3(1024), 0, stream>>>(
        adj, E1g, G1g, E2g, G2g, xtp, out, pvx, s_part);
    k5_reduce<<<dim3(N * CH / 4 / 256), dim3(256), 0, stream>>>(pvx, s_part, out);
}